// Round 1
// baseline (253.672 us; speedup 1.0000x reference)
//
#include <hip/hip_runtime.h>
#include <hip/hip_bf16.h>

#define N_TOT   32768
#define NUMNODE 128
#define NGRAPH  256
#define EDGES   524288
#define HDIM    128
#define MLP_HID 512
#define OUTDIM  10
#define KBIG    16384   // NUMNODE*HDIM
#define CAP     64      // max in-degree bucket capacity (Binomial(2048,1/128)~Poisson(16); P(>64)~0)

typedef __attribute__((ext_vector_type(8))) short  short8;   // 8 x bf16 bits (4 VGPRs)
typedef __attribute__((ext_vector_type(4))) float  floatx4;  // MFMA accumulator

__device__ __forceinline__ unsigned short f2b(float f){
  __hip_bfloat16 h = __float2bfloat16(f);
  union { __hip_bfloat16 h; unsigned short u; } cv; cv.h = h; return cv.u;
}

// ---- degree count + incoming-edge buckets (src local id, 1 byte) ----
__global__ __launch_bounds__(256) void k_fill(const int* __restrict__ ei,
                                              int* __restrict__ cnt,
                                              unsigned char* __restrict__ bucket){
  int e = blockIdx.x*256 + threadIdx.x;
  if (e >= EDGES) return;
  int s = ei[e];            // source
  int d = ei[EDGES + e];    // target (aggregation index)
  int slot = atomicAdd(&cnt[d], 1);
  if (slot < CAP) bucket[(size_t)d*CAP + slot] = (unsigned char)(s & (NUMNODE-1));
}

// ---- dinv = rsqrt(deg + self-loop) ----
__global__ __launch_bounds__(256) void k_dinv(const int* __restrict__ cnt,
                                              float* __restrict__ dinv){
  int i = blockIdx.x*256 + threadIdx.x;
  if (i < N_TOT) dinv[i] = rsqrtf((float)(cnt[i] + 1));
}

// ---- cast x fp32 -> bf16 (vectorized) ----
__global__ __launch_bounds__(256) void k_cast_x(const float* __restrict__ x,
                                                unsigned short* __restrict__ xb){
  int i = blockIdx.x*256 + threadIdx.x;   // 1048576 float4s
  float4 v = ((const float4*)x)[i];
  ushort4 o;
  o.x = f2b(v.x); o.y = f2b(v.y); o.z = f2b(v.z); o.w = f2b(v.w);
  ((ushort4*)xb)[i] = o;
}

// ---- W1/W2 transpose+cast: w_t[n][k] = W[k][n], bf16 (tiny) ----
__global__ __launch_bounds__(256) void k_castT_w(const float* __restrict__ W1,
                                                 const float* __restrict__ W2,
                                                 unsigned short* __restrict__ w1t,
                                                 unsigned short* __restrict__ w2t){
  int idx = blockIdx.x*256 + threadIdx.x;   // < 32768
  int sel = idx >> 14; int i = idx & 16383;
  int k = i >> 7, n = i & 127;
  const float* W = sel ? W2 : W1;
  unsigned short* D = sel ? w2t : w1t;
  D[n*HDIM + k] = f2b(W[k*HDIM + n]);
}

// ---- lin1_w [16384][512] -> transposed bf16 [512][16384], LDS-tiled ----
__global__ __launch_bounds__(256) void k_castT_lin1(const float* __restrict__ W,
                                                    unsigned short* __restrict__ WT){
  __shared__ unsigned short tile[32][33];
  int k0 = blockIdx.x*32, n0 = blockIdx.y*32;
  int lx = threadIdx.x & 31, ly = threadIdx.x >> 5;   // 32x8
  #pragma unroll
  for (int i = 0; i < 4; ++i){
    int k = k0 + ly + i*8;
    tile[ly + i*8][lx] = f2b(W[(size_t)k*MLP_HID + n0 + lx]);
  }
  __syncthreads();
  #pragma unroll
  for (int i = 0; i < 4; ++i){
    int n = n0 + ly + i*8;
    WT[(size_t)n*KBIG + k0 + lx] = tile[lx][ly + i*8];
  }
}

// ---- GEMM: [M x 128] bf16 @ W(via BT[128][128]) -> fp32 [M x 128] ----
// wave computes 16(M) x 64(N); block = 4 waves stacked in M.
__global__ __launch_bounds__(256) void gemm_nk128(const unsigned short* __restrict__ A,
                                                  const unsigned short* __restrict__ BT,
                                                  float* __restrict__ C){
  int wave = threadIdx.x >> 6, lane = threadIdx.x & 63;
  int m0 = blockIdx.x*64 + wave*16;
  int n0 = blockIdx.y*64;
  int r = lane & 15, q = lane >> 4;
  floatx4 z = {0.f,0.f,0.f,0.f};
  floatx4 acc0=z, acc1=z, acc2=z, acc3=z;
  const short8* Ap = (const short8*)(A  + (size_t)(m0 + r)*HDIM + q*8);
  const short8* Bp = (const short8*)(BT + (size_t)(n0 + r)*HDIM + q*8);
  // B subtile stride: 16 rows * 128 = 2048 ushorts = 256 short8
  #pragma unroll
  for (int ks = 0; ks < 4; ++ks){
    short8 a = Ap[ks*4];
    acc0 = __builtin_amdgcn_mfma_f32_16x16x32_bf16(a, Bp[ks*4        ], acc0, 0,0,0);
    acc1 = __builtin_amdgcn_mfma_f32_16x16x32_bf16(a, Bp[ks*4 +  256 ], acc1, 0,0,0);
    acc2 = __builtin_amdgcn_mfma_f32_16x16x32_bf16(a, Bp[ks*4 +  512 ], acc2, 0,0,0);
    acc3 = __builtin_amdgcn_mfma_f32_16x16x32_bf16(a, Bp[ks*4 +  768 ], acc3, 0,0,0);
  }
  float* Crow = C + (size_t)m0*HDIM + n0;
  #pragma unroll
  for (int rr = 0; rr < 4; ++rr){
    int row = q*4 + rr;   // C/D: col=lane&15, row=(lane>>4)*4+reg  [m89]
    Crow[(size_t)row*HDIM +  0 + r] = acc0[rr];
    Crow[(size_t)row*HDIM + 16 + r] = acc1[rr];
    Crow[(size_t)row*HDIM + 32 + r] = acc2[rr];
    Crow[(size_t)row*HDIM + 48 + r] = acc3[rr];
  }
}

// ---- GCN aggregation: per (graph, feature-half). LDS-staged h slice. ----
__global__ __launch_bounds__(256) void k_agg(const float* __restrict__ hlin,
                                             const float* __restrict__ dinv,
                                             const unsigned char* __restrict__ bucket,
                                             const int* __restrict__ cnt,
                                             const float* __restrict__ bias,
                                             unsigned short* __restrict__ hact){
  __shared__ float lds[NUMNODE*64];   // 32 KB: 128 nodes x 64 feats
  int g  = blockIdx.x >> 1;
  int fh = blockIdx.x & 1;
  int t  = threadIdx.x;
  for (int i = t; i < NUMNODE*16; i += 256){
    int node = i >> 4, f4 = i & 15;
    ((float4*)lds)[node*16 + f4] =
      *(const float4*)(hlin + ((size_t)(g*NUMNODE + node))*HDIM + fh*64 + f4*4);
  }
  __syncthreads();
  int lanef = t & 15, w = t >> 4;   // 16 walkers x 8 nodes, 4 feats/thread
  float4 bv = *(const float4*)(bias + fh*64 + lanef*4);
  for (int n = w*8; n < w*8 + 8; ++n){
    int gn = g*NUMNODE + n;
    float din = dinv[gn];
    float4 hv = ((const float4*)lds)[n*16 + lanef];
    float ax = hv.x*din, ay = hv.y*din, az = hv.z*din, aw = hv.w*din; // self-loop
    int c = min(cnt[gn], CAP);
    const unsigned char* bk = bucket + (size_t)gn*CAP;
    for (int s = 0; s < c; ++s){
      int loc = bk[s];
      float dv = dinv[g*NUMNODE + loc];
      float4 m = ((const float4*)lds)[loc*16 + lanef];
      ax += m.x*dv; ay += m.y*dv; az += m.z*dv; aw += m.w*dv;
    }
    ushort4 o;
    o.x = f2b(fmaxf(ax*din + bv.x, 0.f));
    o.y = f2b(fmaxf(ay*din + bv.y, 0.f));
    o.z = f2b(fmaxf(az*din + bv.z, 0.f));
    o.w = f2b(fmaxf(aw*din + bv.w, 0.f));
    *(ushort4*)(hact + (size_t)gn*HDIM + fh*64 + lanef*4) = o;
  }
}

// ---- lin1: [256 x 16384] @ [16384 x 512] via BT, split-K, fp32 atomic reduce ----
__global__ __launch_bounds__(256) void gemm_lin1(const unsigned short* __restrict__ A,
                                                 const unsigned short* __restrict__ BT,
                                                 float* __restrict__ C){
  int wave = threadIdx.x >> 6, lane = threadIdx.x & 63;
  int m0 = blockIdx.x*64 + wave*16;
  int n0 = blockIdx.y*64;
  int k0 = blockIdx.z*2048;
  int r = lane & 15, q = lane >> 4;
  floatx4 z = {0.f,0.f,0.f,0.f};
  floatx4 acc0=z, acc1=z, acc2=z, acc3=z;
  const short8* Ap = (const short8*)(A  + (size_t)(m0 + r)*KBIG + k0 + q*8);
  const short8* Bp = (const short8*)(BT + (size_t)(n0 + r)*KBIG + k0 + q*8);
  // B subtile stride: 16*16384 ushorts = 32768 short8
  #pragma unroll 4
  for (int ks = 0; ks < 64; ++ks){
    short8 a = Ap[ks*4];
    acc0 = __builtin_amdgcn_mfma_f32_16x16x32_bf16(a, Bp[ks*4         ], acc0, 0,0,0);
    acc1 = __builtin_amdgcn_mfma_f32_16x16x32_bf16(a, Bp[ks*4 + 32768 ], acc1, 0,0,0);
    acc2 = __builtin_amdgcn_mfma_f32_16x16x32_bf16(a, Bp[ks*4 + 65536 ], acc2, 0,0,0);
    acc3 = __builtin_amdgcn_mfma_f32_16x16x32_bf16(a, Bp[ks*4 + 98304 ], acc3, 0,0,0);
  }
  #pragma unroll
  for (int rr = 0; rr < 4; ++rr){
    int row = m0 + q*4 + rr;
    atomicAdd(&C[(size_t)row*MLP_HID + n0 +  0 + r], acc0[rr]);
    atomicAdd(&C[(size_t)row*MLP_HID + n0 + 16 + r], acc1[rr]);
    atomicAdd(&C[(size_t)row*MLP_HID + n0 + 32 + r], acc2[rr]);
    atomicAdd(&C[(size_t)row*MLP_HID + n0 + 48 + r], acc3[rr]);
  }
}

// ---- bias + relu on h3 ----
__global__ __launch_bounds__(256) void k_bias_relu(const float* __restrict__ h3,
                                                   const float* __restrict__ b,
                                                   float* __restrict__ h3r){
  int i = blockIdx.x*256 + threadIdx.x;   // 131072
  h3r[i] = fmaxf(h3[i] + b[i & (MLP_HID-1)], 0.f);
}

// ---- lin2: [256 x 512] @ [512 x 10] + b, one wave per row ----
__global__ __launch_bounds__(256) void k_lin2(const float* __restrict__ h3r,
                                              const float* __restrict__ w2,
                                              const float* __restrict__ b2,
                                              float* __restrict__ out){
  int wave = threadIdx.x >> 6, lane = threadIdx.x & 63;
  int m = blockIdx.x*4 + wave;
  float hv[8];
  #pragma unroll
  for (int i = 0; i < 8; ++i) hv[i] = h3r[(size_t)m*MLP_HID + lane + i*64];
  #pragma unroll
  for (int j = 0; j < OUTDIM; ++j){
    float p = 0.f;
    #pragma unroll
    for (int i = 0; i < 8; ++i) p += hv[i] * w2[(lane + i*64)*OUTDIM + j];
    #pragma unroll
    for (int off = 32; off > 0; off >>= 1) p += __shfl_down(p, off);
    if (lane == 0) out[m*OUTDIM + j] = p + b2[j];
  }
}

extern "C" void kernel_launch(void* const* d_in, const int* in_sizes, int n_in,
                              void* d_out, int out_size, void* d_ws, size_t ws_size,
                              hipStream_t stream){
  const float* x   = (const float*)d_in[0];
  const int*   ei  = (const int*)d_in[1];
  const float* W1  = (const float*)d_in[3];
  const float* b1  = (const float*)d_in[4];
  const float* W2  = (const float*)d_in[5];
  const float* b2  = (const float*)d_in[6];
  const float* l1w = (const float*)d_in[7];
  const float* l1b = (const float*)d_in[8];
  const float* l2w = (const float*)d_in[9];
  const float* l2b = (const float*)d_in[10];
  float* out = (float*)d_out;

  char* ws = (char*)d_ws;
  int*            cnt    = (int*)           (ws + 0);          // 128 KB
  float*          dinv   = (float*)         (ws + 131072);     // 128 KB
  unsigned char*  bucket = (unsigned char*) (ws + 262144);     // 2 MB
  unsigned short* xb     = (unsigned short*)(ws + 2359296);    // 8 MB
  unsigned short* w1t    = (unsigned short*)(ws + 10747904);   // 32 KB
  unsigned short* w2t    = (unsigned short*)(ws + 10780672);   // 32 KB
  unsigned short* l1wt   = (unsigned short*)(ws + 10813440);   // 16 MB
  float*          hlin   = (float*)         (ws + 27590656);   // 16 MB
  unsigned short* hact   = (unsigned short*)(ws + 44367872);   // 8 MB
  float*          h3     = (float*)         (ws + 52756480);   // 512 KB
  float*          h3r    = (float*)         (ws + 53280768);   // 512 KB

  hipMemsetAsync(cnt, 0, 131072, stream);
  hipMemsetAsync(h3, 0, 524288, stream);

  k_fill      <<<EDGES/256, 256, 0, stream>>>(ei, cnt, bucket);
  k_dinv      <<<N_TOT/256, 256, 0, stream>>>(cnt, dinv);
  k_cast_x    <<<4096, 256, 0, stream>>>(x, xb);
  k_castT_w   <<<128, 256, 0, stream>>>(W1, W2, w1t, w2t);
  k_castT_lin1<<<dim3(KBIG/32, MLP_HID/32), 256, 0, stream>>>(l1w, l1wt);

  gemm_nk128  <<<dim3(N_TOT/64, 2), 256, 0, stream>>>(xb, w1t, hlin);
  k_agg       <<<2*NGRAPH, 256, 0, stream>>>(hlin, dinv, bucket, cnt, b1, hact);
  gemm_nk128  <<<dim3(N_TOT/64, 2), 256, 0, stream>>>(hact, w2t, hlin);
  k_agg       <<<2*NGRAPH, 256, 0, stream>>>(hlin, dinv, bucket, cnt, b2, hact);

  gemm_lin1   <<<dim3(4, 8, 8), 256, 0, stream>>>(hact, l1wt, h3);
  k_bias_relu <<<512, 256, 0, stream>>>(h3, l1b, h3r);
  k_lin2      <<<NGRAPH/4, 256, 0, stream>>>(h3r, l2w, l2b, out);
}